// Round 11
// baseline (126.373 us; speedup 1.0000x reference)
//
#include <hip/hip_runtime.h>
#include <hip/hip_bf16.h>

// CARNN: 9-step RNN (D=64) + projection to 300 actions, BATCH=65536.
// R14 (resubmit; previous round failed on container acquisition, kernel
// never ran). Measured phase decomposition. Five structural theories in
// a row were nulls (~51 us regardless); the RNN=38us / proj=13us split
// was MODELED, never measured. Split into carnn_rnn (R13 RNN verbatim;
// s8's H stored straight to global scratch; no projection, 1 barrier)
// and carnn_proj (H read as coalesced B-frags from global -- row-major
// IS the frag layout; out_w in LDS; 512x512thr = 24 waves/CU). Each
// phase gets its own dur_us + counters. Handoff: 8MB w + 8MB r (~3us).
// ws_size guard: if workspace < 8.6MB, fall back to the known-good R13
// single kernel (profile kernel names show which path ran).

#define SEQ     9
#define DMODEL  64
#define ANUM    300

// ws layout (bf16 element offsets) -- unchanged, prepack identical
#define WS_MW   0        // 9*8192: per step [kind(M=0,W=1)][nt][kb][lane][8]
#define WS_OW   73728    // 5*4096: [cc][nt][kb][lane][8]
#define WS_EMB  94208    // 301*64 bf16 emb table
#define WS_END  113472
#define WS_BSUM_BYTES (WS_END * 2)
#define WS_HG_SH  118784              // H scratch, shorts (byte 237,568)
#define WS_NEED_BYTES (WS_HG_SH * 2 + 65536 * 64 * 2)   // 8,626,176

// LDS layout (shorts): weights s0M(4096) + s1..7(7*8192) | bsum | scratch
#define BSOFF   61440
#define HSOFF   62592     // 16 waves x 1024 shorts (2KB each)
#define SLTOT   78976     // 157,952 bytes

typedef __attribute__((ext_vector_type(8))) short  bf16x8;
typedef __attribute__((ext_vector_type(4))) float  f32x4;

#define MFMA __builtin_amdgcn_mfma_f32_16x16x32_bf16

__device__ __forceinline__ unsigned short f2b(float f) {
    union { float f; unsigned int u; } x; x.f = f;
    unsigned int r = x.u + 0x7FFFu + ((x.u >> 16) & 1u);
    return (unsigned short)(r >> 16);
}

__device__ __forceinline__ float sigmoid_fast(float v) {
    return __builtin_amdgcn_rcpf(1.f + __expf(-v));
}

// async global->LDS, 16 B per lane; lds base must be wave-uniform
__device__ __forceinline__ void async16(const unsigned short* g, unsigned short* l) {
    __builtin_amdgcn_global_load_lds(
        (const __attribute__((address_space(1))) unsigned int*)g,
        (__attribute__((address_space(3))) unsigned int*)l, 16, 0, 0);
}

// ---------------- pre-pass: convert + pack (unchanged) ----------------
#define PP_TOTAL (73728 + 20480 + 19264 + 576)

__global__ void prepack(const float* __restrict__ Mw, const float* __restrict__ Ww,
                        const float* __restrict__ outw, const float* __restrict__ emb,
                        const float* __restrict__ Mb, const float* __restrict__ Wb,
                        unsigned short* __restrict__ wsb, float* __restrict__ bsum)
{
    int t = blockIdx.x * 256 + threadIdx.x;
    if (t < 73728) {                       // M+W, step-major 16KB blocks
        int s    = t >> 13;
        int r    = t & 8191;
        int kind = r >> 12;
        int f    = r & 4095;
        int nt   = f >> 10;
        int kb   = (f >> 9) & 1;
        int lane = (f >> 3) & 63;
        int j    = f & 7;
        int nr   = nt * 16 + (lane & 15);
        int k    = kb * 32 + ((lane >> 4) << 3) + j;
        const float* src = kind ? Ww : Mw;
        wsb[WS_MW + t] = f2b(src[(s * DMODEL + nr) * DMODEL + k]);
        return;
    }
    t -= 73728;
    if (t < 20480) {                       // outw fragments
        int j    = t & 7;
        int lane = (t >> 3) & 63;
        int kb   = (t >> 9) & 1;
        int nt   = (t >> 10) & 3;
        int cc   = t >> 12;
        int col  = cc * 64 + nt * 16 + (lane & 15);
        int k    = kb * 32 + ((lane >> 4) << 3) + j;
        float v  = (col < ANUM) ? outw[col * DMODEL + k] : 0.f;
        wsb[WS_OW + t] = f2b(v);
        return;
    }
    t -= 20480;
    if (t < 19264) { wsb[WS_EMB + t] = f2b(emb[t]); return; }
    t -= 19264;
    if (t < 576)   { bsum[t] = Mb[t] + Wb[t]; }
}

// ================= SPLIT PATH: kernel A (RNN only) =================
__global__ __launch_bounds__(1024, 4)
void carnn_rnn(const int* __restrict__ acts,
               const unsigned short* __restrict__ wsb,
               const float* __restrict__ bsum,
               unsigned short* __restrict__ Hg)
{
    __shared__ __align__(16) unsigned short SL[SLTOT];

    const int tid  = threadIdx.x;
    const int lane = tid & 63;
    const int wv   = tid >> 6;
    const int lrow = lane & 15;
    const int quad = lane >> 4;

    const int brow = (blockIdx.x * 16 + wv) * 16 + lrow;
    const int rowS = brow * SEQ;

    for (int c = wv; c < 120; c += 16) {
        const int goff = (c < 8) ? (c * 512) : ((c + 8) * 512);
        async16(wsb + WS_MW + goff + lane * 8, &SL[c * 512]);
    }
    {
        const unsigned short* bs = (const unsigned short*)bsum;
        if (wv == 13) async16(bs + lane * 8,         &SL[BSOFF]);
        if (wv == 14) async16(bs + 512 + lane * 8,   &SL[BSOFF + 512]);
        if (wv == 15 && lane < 16)
                      async16(bs + 1024 + lane * 8,  &SL[BSOFF + 1024]);
    }

    const unsigned short* Eb = wsb + WS_EMB;
    int id0  = acts[rowS];
    int id1  = acts[rowS + 1];
    int idn2 = acts[rowS + 2];
    bf16x8 xc0 = *(const bf16x8*)(Eb + id0 * DMODEL + quad * 8);
    bf16x8 xc1 = *(const bf16x8*)(Eb + id0 * DMODEL + 32 + quad * 8);
    bf16x8 xn0 = *(const bf16x8*)(Eb + id1 * DMODEL + quad * 8);
    bf16x8 xn1 = *(const bf16x8*)(Eb + id1 * DMODEL + 32 + quad * 8);

    char* const SB = (char*)SL;
    const int swz    = (lrow & 7) << 4;
    const int hbyte  = HSOFF * 2 + wv * 2048 + lrow * 128;
    const int rbyte0 = hbyte + ((quad * 16) ^ swz);
    const int rbyte1 = hbyte + ((64 + quad * 16) ^ swz);

    __syncthreads();    // the only barrier

    const float* BSf = (const float*)&SL[BSOFF];

    f32x4 xacc[4];
    #pragma unroll
    for (int nt = 0; nt < 4; ++nt) {
        const unsigned short* Mf = &SL[nt * 1024 + lane * 8];
        bf16x8 am0 = *(const bf16x8*)Mf;
        bf16x8 am1 = *(const bf16x8*)(Mf + 512);
        f32x4 a = *(const f32x4*)(BSf + nt * 16 + quad * 4);
        a = MFMA(am0, xc0, a, 0, 0, 0);
        a = MFMA(am1, xc1, a, 0, 0, 0);
        xacc[nt] = a;
    }

    #pragma unroll
    for (int s = 0; s < SEQ; ++s) {
        bf16x8 xm0, xm1;
        if (s + 2 < SEQ) {
            xm0 = *(const bf16x8*)(Eb + idn2 * DMODEL + quad * 8);
            xm1 = *(const bf16x8*)(Eb + idn2 * DMODEL + 32 + quad * 8);
            if (s + 3 < SEQ) idn2 = acts[rowS + s + 3];
        }
        bf16x8 h0, h1;
        if (s > 0) {
            h0 = *(const bf16x8*)(SB + rbyte0);
            h1 = *(const bf16x8*)(SB + rbyte1);
        }
        const unsigned short* WBh = (s == 0) ? (const unsigned short*)nullptr
                                  : (s < 8)  ? &SL[4096 + (s - 1) * 8192 + 4096]
                                             : wsb + WS_MW + 8 * 8192 + 4096;
        #pragma unroll
        for (int nt = 0; nt < 4; ++nt) {
            f32x4 acc = xacc[nt];
            if (s > 0) {
                const unsigned short* Wf = WBh + nt * 1024 + lane * 8;
                bf16x8 aw0 = *(const bf16x8*)Wf;
                bf16x8 aw1 = *(const bf16x8*)(Wf + 512);
                acc = MFMA(aw0, h0, acc, 0, 0, 0);
                acc = MFMA(aw1, h1, acc, 0, 0, 0);
            }
            unsigned int u0 = (unsigned int)f2b(sigmoid_fast(acc[0]))
                            | ((unsigned int)f2b(sigmoid_fast(acc[1])) << 16);
            unsigned int u1 = (unsigned int)f2b(sigmoid_fast(acc[2]))
                            | ((unsigned int)f2b(sigmoid_fast(acc[3])) << 16);
            if (s < 8) {   // steps 0-7: wave-private LDS scratch
                *(uint2*)(SB + hbyte + ((nt * 32 + quad * 8) ^ swz)) = make_uint2(u0, u1);
            } else {       // step 8: final H -> global, row-major bf16
                *(uint2*)(Hg + brow * 64 + nt * 16 + quad * 4) = make_uint2(u0, u1);
            }
        }
        asm volatile("" ::: "memory");   // pin H write->read order (TBAA)

        if (s + 1 < SEQ) {
            const unsigned short* WBm = (s + 1 < 8) ? &SL[4096 + s * 8192]
                                                    : wsb + WS_MW + 8 * 8192;
            #pragma unroll
            for (int nt = 0; nt < 4; ++nt) {
                const unsigned short* Mf = WBm + nt * 1024 + lane * 8;
                bf16x8 am0 = *(const bf16x8*)Mf;
                bf16x8 am1 = *(const bf16x8*)(Mf + 512);
                f32x4 a = *(const f32x4*)(BSf + (s + 1) * 64 + nt * 16 + quad * 4);
                a = MFMA(am0, xn0, a, 0, 0, 0);
                a = MFMA(am1, xn1, a, 0, 0, 0);
                xacc[nt] = a;
            }
            if (s + 2 < SEQ) { xn0 = xm0; xn1 = xm1; }
        }
    }
}

// ================= SPLIT PATH: kernel B (projection) =================
#define PB_OB 20480          // outb offset in PL (shorts)

__global__ __launch_bounds__(512, 6)
void carnn_proj(const unsigned short* __restrict__ wsb,
                const float* __restrict__ outb,
                const unsigned short* __restrict__ Hg,
                float* __restrict__ out)
{
    __shared__ __align__(16) unsigned short PL[20480 + 768];

    const int tid  = threadIdx.x;
    const int lane = tid & 63;
    const int wv   = tid >> 6;         // 0..7
    const int lrow = lane & 15;
    const int quad = lane >> 4;

    const int brow = blockIdx.x * 128 + wv * 16 + lrow;

    // stage out_w (40KB) + outb (1.2KB)
    for (int c = wv; c < 40; c += 8)
        async16(wsb + WS_OW + c * 512 + lane * 8, &PL[c * 512]);
    {
        const unsigned short* ob = (const unsigned short*)outb;
        if (wv == 0)              async16(ob + lane * 8,       &PL[PB_OB]);
        if (wv == 1 && lane < 11) async16(ob + 512 + lane * 8, &PL[PB_OB + 512]);
    }

    // H as B-fragments, straight from global (coalesced: rows 128B apart,
    // quads 16B apart -> contiguous 64B per row-half)
    const unsigned short* hrow = Hg + brow * 64;
    bf16x8 h0 = *(const bf16x8*)(hrow + quad * 8);
    bf16x8 h1 = *(const bf16x8*)(hrow + 32 + quad * 8);

    __syncthreads();    // staging complete

    const float* OBf = (const float*)&PL[PB_OB];
    float* orow = out + brow * ANUM;

    #pragma unroll
    for (int t = 0; t < 19; ++t) {
        const int cc = t >> 2, nt = t & 3;
        const unsigned short* Of = &PL[cc * 4096 + nt * 1024 + lane * 8];
        bf16x8 a0 = *(const bf16x8*)Of;
        bf16x8 a1 = *(const bf16x8*)(Of + 512);
        const int col0 = cc * 64 + nt * 16 + quad * 4;

        f32x4 acc;
        if (col0 < ANUM) acc = *(const f32x4*)(OBf + col0);
        else             acc = (f32x4){0.f, 0.f, 0.f, 0.f};
        acc = MFMA(a0, h0, acc, 0, 0, 0);
        acc = MFMA(a1, h1, acc, 0, 0, 0);

        if (col0 < ANUM)
            *(f32x4*)(orow + col0) = acc;
    }
}

// ============== FALLBACK: R13 single kernel (known good) ==============
__global__ __launch_bounds__(1024, 4)
void carnn_main(const int* __restrict__ acts,
                const unsigned short* __restrict__ wsb,
                const float* __restrict__ bsum,
                const float* __restrict__ outb,
                float* __restrict__ out)
{
    __shared__ __align__(16) unsigned short SL[SLTOT];

    const int tid  = threadIdx.x;
    const int lane = tid & 63;
    const int wv   = tid >> 6;
    const int lrow = lane & 15;
    const int quad = lane >> 4;

    const int brow = (blockIdx.x * 16 + wv) * 16 + lrow;
    const int rowS = brow * SEQ;

    for (int c = wv; c < 120; c += 16) {
        const int goff = (c < 8) ? (c * 512) : ((c + 8) * 512);
        async16(wsb + WS_MW + goff + lane * 8, &SL[c * 512]);
    }
    {
        const unsigned short* bs = (const unsigned short*)bsum;
        if (wv == 13) async16(bs + lane * 8,         &SL[BSOFF]);
        if (wv == 14) async16(bs + 512 + lane * 8,   &SL[BSOFF + 512]);
        if (wv == 15 && lane < 16)
                      async16(bs + 1024 + lane * 8,  &SL[BSOFF + 1024]);
    }

    const unsigned short* Eb = wsb + WS_EMB;
    int id0  = acts[rowS];
    int id1  = acts[rowS + 1];
    int idn2 = acts[rowS + 2];
    bf16x8 xc0 = *(const bf16x8*)(Eb + id0 * DMODEL + quad * 8);
    bf16x8 xc1 = *(const bf16x8*)(Eb + id0 * DMODEL + 32 + quad * 8);
    bf16x8 xn0 = *(const bf16x8*)(Eb + id1 * DMODEL + quad * 8);
    bf16x8 xn1 = *(const bf16x8*)(Eb + id1 * DMODEL + 32 + quad * 8);

    char* const SB = (char*)SL;
    const int swz    = (lrow & 7) << 4;
    const int hbyte  = HSOFF * 2 + wv * 2048 + lrow * 128;
    const int rbyte0 = hbyte + ((quad * 16) ^ swz);
    const int rbyte1 = hbyte + ((64 + quad * 16) ^ swz);

    __syncthreads();

    const float* BSf = (const float*)&SL[BSOFF];

    f32x4 xacc[4];
    #pragma unroll
    for (int nt = 0; nt < 4; ++nt) {
        const unsigned short* Mf = &SL[nt * 1024 + lane * 8];
        bf16x8 am0 = *(const bf16x8*)Mf;
        bf16x8 am1 = *(const bf16x8*)(Mf + 512);
        f32x4 a = *(const f32x4*)(BSf + nt * 16 + quad * 4);
        a = MFMA(am0, xc0, a, 0, 0, 0);
        a = MFMA(am1, xc1, a, 0, 0, 0);
        xacc[nt] = a;
    }

    #pragma unroll
    for (int s = 0; s < SEQ; ++s) {
        bf16x8 xm0, xm1;
        if (s + 2 < SEQ) {
            xm0 = *(const bf16x8*)(Eb + idn2 * DMODEL + quad * 8);
            xm1 = *(const bf16x8*)(Eb + idn2 * DMODEL + 32 + quad * 8);
            if (s + 3 < SEQ) idn2 = acts[rowS + s + 3];
        }
        bf16x8 h0, h1;
        if (s > 0) {
            h0 = *(const bf16x8*)(SB + rbyte0);
            h1 = *(const bf16x8*)(SB + rbyte1);
        }
        const unsigned short* WBh = (s == 0) ? (const unsigned short*)nullptr
                                  : (s < 8)  ? &SL[4096 + (s - 1) * 8192 + 4096]
                                             : wsb + WS_MW + 8 * 8192 + 4096;
        #pragma unroll
        for (int nt = 0; nt < 4; ++nt) {
            f32x4 acc = xacc[nt];
            if (s > 0) {
                const unsigned short* Wf = WBh + nt * 1024 + lane * 8;
                bf16x8 aw0 = *(const bf16x8*)Wf;
                bf16x8 aw1 = *(const bf16x8*)(Wf + 512);
                acc = MFMA(aw0, h0, acc, 0, 0, 0);
                acc = MFMA(aw1, h1, acc, 0, 0, 0);
            }
            unsigned int u0 = (unsigned int)f2b(sigmoid_fast(acc[0]))
                            | ((unsigned int)f2b(sigmoid_fast(acc[1])) << 16);
            unsigned int u1 = (unsigned int)f2b(sigmoid_fast(acc[2]))
                            | ((unsigned int)f2b(sigmoid_fast(acc[3])) << 16);
            *(uint2*)(SB + hbyte + ((nt * 32 + quad * 8) ^ swz)) = make_uint2(u0, u1);
        }
        asm volatile("" ::: "memory");

        if (s + 1 < SEQ) {
            const unsigned short* WBm = (s + 1 < 8) ? &SL[4096 + s * 8192]
                                                    : wsb + WS_MW + 8 * 8192;
            #pragma unroll
            for (int nt = 0; nt < 4; ++nt) {
                const unsigned short* Mf = WBm + nt * 1024 + lane * 8;
                bf16x8 am0 = *(const bf16x8*)Mf;
                bf16x8 am1 = *(const bf16x8*)(Mf + 512);
                f32x4 a = *(const f32x4*)(BSf + (s + 1) * 64 + nt * 16 + quad * 4);
                a = MFMA(am0, xn0, a, 0, 0, 0);
                a = MFMA(am1, xn1, a, 0, 0, 0);
                xacc[nt] = a;
            }
            if (s + 2 < SEQ) { xn0 = xm0; xn1 = xm1; }
        }
    }

    bf16x8 h0 = *(const bf16x8*)(SB + rbyte0);
    bf16x8 h1 = *(const bf16x8*)(SB + rbyte1);

    __syncthreads();
    for (int c = wv; c < 40; c += 16)
        async16(wsb + WS_OW + c * 512 + lane * 8, &SL[c * 512]);
    {
        const unsigned short* ob = (const unsigned short*)outb;
        if (wv == 12)               async16(ob + lane * 8,       &SL[BSOFF]);
        if (wv == 13 && lane < 11)  async16(ob + 512 + lane * 8, &SL[BSOFF + 512]);
    }
    __syncthreads();

    const float* OBf = (const float*)&SL[BSOFF];
    float* orow = out + brow * ANUM;

    #pragma unroll
    for (int t = 0; t < 19; ++t) {
        const int cc = t >> 2, nt = t & 3;
        const unsigned short* Of = &SL[cc * 4096 + nt * 1024 + lane * 8];
        bf16x8 a0 = *(const bf16x8*)Of;
        bf16x8 a1 = *(const bf16x8*)(Of + 512);
        const int col0 = cc * 64 + nt * 16 + quad * 4;

        f32x4 acc;
        if (col0 < ANUM) acc = *(const f32x4*)(OBf + col0);
        else             acc = (f32x4){0.f, 0.f, 0.f, 0.f};
        acc = MFMA(a0, h0, acc, 0, 0, 0);
        acc = MFMA(a1, h1, acc, 0, 0, 0);

        if (col0 < ANUM)
            *(f32x4*)(orow + col0) = acc;
    }
}

extern "C" void kernel_launch(void* const* d_in, const int* in_sizes, int n_in,
                              void* d_out, int out_size, void* d_ws, size_t ws_size,
                              hipStream_t stream) {
    const int*   acts = (const int*)  d_in[0];
    const float* emb  = (const float*)d_in[1];
    const float* Mw   = (const float*)d_in[2];
    const float* Mb   = (const float*)d_in[3];
    const float* Ww   = (const float*)d_in[4];
    const float* Wb   = (const float*)d_in[5];
    const float* outw = (const float*)d_in[6];
    const float* outb = (const float*)d_in[7];
    float* out = (float*)d_out;
    (void)in_sizes; (void)n_in; (void)out_size;

    unsigned short* wsb = (unsigned short*)d_ws;
    float* bsum = (float*)((char*)d_ws + WS_BSUM_BYTES);

    prepack<<<(PP_TOTAL + 255) / 256, 256, 0, stream>>>(Mw, Ww, outw, emb, Mb, Wb, wsb, bsum);

    if (ws_size >= (size_t)WS_NEED_BYTES) {
        unsigned short* Hg = wsb + WS_HG_SH;
        carnn_rnn <<<65536 / 256, 1024, 0, stream>>>(acts, wsb, bsum, Hg);
        carnn_proj<<<65536 / 128,  512, 0, stream>>>(wsb, outb, Hg, out);
    } else {
        carnn_main<<<65536 / 256, 1024, 0, stream>>>(acts, wsb, bsum, outb, out);
    }
}